// Round 1
// baseline (647.243 us; speedup 1.0000x reference)
//
#include <hip/hip_runtime.h>
#include <hip/hip_bf16.h>

#define NEG_SLOPE 0.2f

// ---------------------------------------------------------------- CSR build
__global__ void k_hist(const int* __restrict__ dst, int E, int n, int* __restrict__ deg) {
    int e = blockIdx.x * blockDim.x + threadIdx.x;
    int ET = E + n;
    if (e >= ET) return;
    int d = (e < E) ? dst[e] : (e - E);   // self-loops appended
    atomicAdd(&deg[d], 1);
}

__global__ void k_scan(const int* __restrict__ deg, int* __restrict__ rowptr,
                       int* __restrict__ cursor, int n) {
    __shared__ int part[256];
    int t = threadIdx.x;
    int chunk = (n + 255) / 256;
    int s0 = t * chunk, s1 = min(s0 + chunk, n);
    int s = 0;
    for (int i = s0; i < s1; ++i) s += deg[i];
    part[t] = s;
    __syncthreads();
    // Hillis-Steele inclusive scan
    for (int off = 1; off < 256; off <<= 1) {
        int v = (t >= off) ? part[t - off] : 0;
        __syncthreads();
        part[t] += v;
        __syncthreads();
    }
    int run = (t == 0) ? 0 : part[t - 1];
    for (int i = s0; i < s1; ++i) { rowptr[i] = run; cursor[i] = run; run += deg[i]; }
    if (t == 255) rowptr[n] = run;
}

__global__ void k_scatter(const int* __restrict__ src, const int* __restrict__ dst,
                          int E, int n, int* __restrict__ cursor, int* __restrict__ csr_src) {
    int e = blockIdx.x * blockDim.x + threadIdx.x;
    int ET = E + n;
    if (e >= ET) return;
    int s = (e < E) ? src[e] : (e - E);
    int d = (e < E) ? dst[e] : (e - E);
    int pos = atomicAdd(&cursor[d], 1);
    csr_src[pos] = s;
}

// ---------------------------------------------------------------- fp32 GEMM
// C[M,N] = A[M,K] @ B[K,N], row-major. BM=BN=64, BK=32, 256 thr, 4x4/thread.
template <int BM, int BN, int BK>
__global__ __launch_bounds__(256) void k_sgemm(const float* __restrict__ A,
                                               const float* __restrict__ B,
                                               float* __restrict__ C,
                                               int M, int N, int K) {
    __shared__ float As[BM][BK + 1];   // +1 pad: conflict-free column reads
    __shared__ float Bs[BK][BN];
    int t = threadIdx.x;
    int tx = t & 15, ty = t >> 4;
    int row0 = blockIdx.y * BM, col0 = blockIdx.x * BN;
    float acc[4][4] = {};
    for (int kt = 0; kt < K; kt += BK) {
#pragma unroll
        for (int l = 0; l < (BM * BK) / (256 * 4); ++l) {
            int idx = t + l * 256;            // float4 index
            int r = idx / (BK / 4);
            int c4 = idx % (BK / 4);
            int gr = row0 + r; if (gr >= M) gr = M - 1;   // clamp (dup rows, harmless)
            const float4 v = *reinterpret_cast<const float4*>(&A[(size_t)gr * K + kt + c4 * 4]);
            As[r][c4 * 4 + 0] = v.x; As[r][c4 * 4 + 1] = v.y;
            As[r][c4 * 4 + 2] = v.z; As[r][c4 * 4 + 3] = v.w;
        }
#pragma unroll
        for (int l = 0; l < (BK * BN) / (256 * 4); ++l) {
            int idx = t + l * 256;
            int r = idx / (BN / 4);
            int c4 = idx % (BN / 4);
            const float4 v = *reinterpret_cast<const float4*>(&B[(size_t)(kt + r) * N + col0 + c4 * 4]);
            *reinterpret_cast<float4*>(&Bs[r][c4 * 4]) = v;
        }
        __syncthreads();
#pragma unroll
        for (int k = 0; k < BK; ++k) {
            float a[4];
#pragma unroll
            for (int i = 0; i < 4; ++i) a[i] = As[ty * 4 + i][k];
            float4 bv = *reinterpret_cast<const float4*>(&Bs[k][tx * 4]);
            float b[4] = {bv.x, bv.y, bv.z, bv.w};
#pragma unroll
            for (int i = 0; i < 4; ++i)
#pragma unroll
                for (int j = 0; j < 4; ++j) acc[i][j] = fmaf(a[i], b[j], acc[i][j]);
        }
        __syncthreads();
    }
#pragma unroll
    for (int i = 0; i < 4; ++i) {
        int gr = row0 + ty * 4 + i;
        if (gr < M) {
            float4 v = {acc[i][0], acc[i][1], acc[i][2], acc[i][3]};
            *reinterpret_cast<float4*>(&C[(size_t)gr * N + col0 + tx * 4]) = v;
        }
    }
}

// ------------------------------------------------------- attention logit dots
// al_s[n,h] = dot(h[n,h,:], att_src[h,:]);  al_d likewise. One wave per (n,h).
template <int H, int C>
__global__ void k_att(const float* __restrict__ h, const float* __restrict__ as,
                      const float* __restrict__ ad, float* __restrict__ al_s,
                      float* __restrict__ al_d, int n) {
    int wave = (blockIdx.x * blockDim.x + threadIdx.x) >> 6;
    int lane = threadIdx.x & 63;
    if (wave >= n * H) return;
    int node = wave / H, hh = wave % H;
    const float* hp = h + (size_t)node * H * C + hh * C;
    float aS = 0.f, aD = 0.f;
    for (int c = lane; c < C; c += 64) {
        float v = hp[c];
        aS += v * as[hh * C + c];
        aD += v * ad[hh * C + c];
    }
#pragma unroll
    for (int off = 32; off > 0; off >>= 1) {
        aS += __shfl_down(aS, off);
        aD += __shfl_down(aD, off);
    }
    if (lane == 0) { al_s[wave] = aS; al_d[wave] = aD; }
}

// ----------------------------------------------- per-node softmax + aggregate
// out[n, h*C+c] = relu( bias + sum_e alpha_e,h * h[src_e, h*C+c] )
template <int H, int C>
__global__ __launch_bounds__(256) void k_agg(const float* __restrict__ h,
                                             const float* __restrict__ al_s,
                                             const float* __restrict__ al_d,
                                             const int* __restrict__ rowptr,
                                             const int* __restrict__ csr_src,
                                             const float* __restrict__ bias,
                                             float* __restrict__ out) {
    constexpr int HC = H * C;
    constexpr int PT = (HC + 255) / 256;
    constexpr int CHUNK = 128;
    int node = blockIdx.x, t = threadIdx.x;
    int beg = rowptr[node], end = rowptr[node + 1];

    __shared__ float s_red[256];
    __shared__ float s_m[H], s_inv[H];
    __shared__ float s_alpha[CHUNK * H];
    __shared__ int s_src[CHUNK];

    float ald[H];
#pragma unroll
    for (int hh = 0; hh < H; ++hh) ald[hh] = al_d[node * H + hh];

    // pass 1: per-head max of leaky_relu logits
    float mx[H];
#pragma unroll
    for (int hh = 0; hh < H; ++hh) mx[hh] = -1e30f;
    for (int i = beg + t; i < end; i += 256) {
        int s = csr_src[i];
#pragma unroll
        for (int hh = 0; hh < H; ++hh) {
            float e = al_s[s * H + hh] + ald[hh];
            e = e > 0.f ? e : NEG_SLOPE * e;
            mx[hh] = fmaxf(mx[hh], e);
        }
    }
#pragma unroll
    for (int hh = 0; hh < H; ++hh) {
        s_red[t] = mx[hh]; __syncthreads();
        for (int off = 128; off > 0; off >>= 1) {
            if (t < off) s_red[t] = fmaxf(s_red[t], s_red[t + off]);
            __syncthreads();
        }
        if (t == 0) s_m[hh] = s_red[0];
        __syncthreads();
    }

    // pass 2: denom
    float sm[H];
#pragma unroll
    for (int hh = 0; hh < H; ++hh) sm[hh] = 0.f;
    for (int i = beg + t; i < end; i += 256) {
        int s = csr_src[i];
#pragma unroll
        for (int hh = 0; hh < H; ++hh) {
            float e = al_s[s * H + hh] + ald[hh];
            e = e > 0.f ? e : NEG_SLOPE * e;
            sm[hh] += __expf(e - s_m[hh]);
        }
    }
#pragma unroll
    for (int hh = 0; hh < H; ++hh) {
        s_red[t] = sm[hh]; __syncthreads();
        for (int off = 128; off > 0; off >>= 1) {
            if (t < off) s_red[t] += s_red[t + off];
            __syncthreads();
        }
        if (t == 0) s_inv[hh] = 1.f / s_red[0];
        __syncthreads();
    }

    // pass 3: chunked weighted aggregation (no atomics)
    int hd[PT];
#pragma unroll
    for (int k = 0; k < PT; ++k) hd[k] = (t + k * 256) / C;
    float acc[PT];
#pragma unroll
    for (int k = 0; k < PT; ++k) acc[k] = 0.f;

    for (int cs = beg; cs < end; cs += CHUNK) {
        int cnt = min(CHUNK, end - cs);
        __syncthreads();
        for (int i = t; i < cnt; i += 256) {
            int s = csr_src[cs + i];
            s_src[i] = s;
#pragma unroll
            for (int hh = 0; hh < H; ++hh) {
                float e = al_s[s * H + hh] + ald[hh];
                e = e > 0.f ? e : NEG_SLOPE * e;
                s_alpha[i * H + hh] = __expf(e - s_m[hh]) * s_inv[hh];
            }
        }
        __syncthreads();
        for (int j = 0; j < cnt; ++j) {
            const float* hrow = h + (size_t)s_src[j] * HC;
#pragma unroll
            for (int k = 0; k < PT; ++k) {
                int ch = t + k * 256;
                if (HC % 256 == 0 || ch < HC)
                    acc[k] = fmaf(s_alpha[j * H + hd[k]], hrow[ch], acc[k]);
            }
        }
    }

#pragma unroll
    for (int k = 0; k < PT; ++k) {
        int ch = t + k * 256;
        if (HC % 256 == 0 || ch < HC) {
            float v = acc[k] + bias[ch];
            out[(size_t)node * HC + ch] = v > 0.f ? v : 0.f;
        }
    }
}

// ---------------------------------------------------------------------- host
extern "C" void kernel_launch(void* const* d_in, const int* in_sizes, int n_in,
                              void* d_out, int out_size, void* d_ws, size_t ws_size,
                              hipStream_t stream) {
    const float* x   = (const float*)d_in[0];
    const int*   ei  = (const int*)d_in[1];
    const float* W1  = (const float*)d_in[2];
    const float* as1 = (const float*)d_in[3];
    const float* ad1 = (const float*)d_in[4];
    const float* b1  = (const float*)d_in[5];
    const float* W2  = (const float*)d_in[6];
    const float* as2 = (const float*)d_in[7];
    const float* ad2 = (const float*)d_in[8];
    const float* b2  = (const float*)d_in[9];
    float* out = (float*)d_out;

    const int N  = in_sizes[0] / 128;   // 20000
    const int E  = in_sizes[1] / 2;     // 320000
    const int ET = E + N;
    const int* src = ei;
    const int* dst = ei + E;

    char* ws = (char*)d_ws;
    size_t off = 0;
    auto alloc = [&](size_t bytes) {
        void* p = ws + off;
        off = (off + bytes + 255) & ~(size_t)255;
        return p;
    };
    float* h1   = (float*)alloc((size_t)N * 768 * 4);
    float* x2   = (float*)alloc((size_t)N * 768 * 4);
    float* h2   = (float*)alloc((size_t)N * 384 * 4);
    float* alS1 = (float*)alloc((size_t)N * 3 * 4);
    float* alD1 = (float*)alloc((size_t)N * 3 * 4);
    float* alS2 = (float*)alloc((size_t)N * 4);
    float* alD2 = (float*)alloc((size_t)N * 4);
    int* deg    = (int*)alloc((size_t)N * 4);
    int* rowptr = (int*)alloc((size_t)(N + 1) * 4);
    int* cursor = (int*)alloc((size_t)N * 4);
    int* csrs   = (int*)alloc((size_t)ET * 4);

    // CSR by destination (shared by both layers)
    hipMemsetAsync(deg, 0, (size_t)N * 4, stream);
    k_hist<<<(ET + 255) / 256, 256, 0, stream>>>(dst, E, N, deg);
    k_scan<<<1, 256, 0, stream>>>(deg, rowptr, cursor, N);
    k_scatter<<<(ET + 255) / 256, 256, 0, stream>>>(src, dst, E, N, cursor, csrs);

    // layer 1
    dim3 g1(768 / 64, (N + 63) / 64);
    k_sgemm<64, 64, 32><<<g1, 256, 0, stream>>>(x, W1, h1, N, 768, 128);
    k_att<3, 256><<<(N * 3 + 3) / 4, 256, 0, stream>>>(h1, as1, ad1, alS1, alD1, N);
    k_agg<3, 256><<<N, 256, 0, stream>>>(h1, alS1, alD1, rowptr, csrs, b1, x2);

    // layer 2
    dim3 g2(384 / 64, (N + 63) / 64);
    k_sgemm<64, 64, 32><<<g2, 256, 0, stream>>>(x2, W2, h2, N, 384, 768);
    k_att<1, 384><<<(N + 3) / 4, 256, 0, stream>>>(h2, as2, ad2, alS2, alD2, N);
    k_agg<1, 384><<<N, 256, 0, stream>>>(h2, alS2, alD2, rowptr, csrs, b2, out);
}

// Round 2
// 484.563 us; speedup vs baseline: 1.3357x; 1.3357x over previous
//
#include <hip/hip_runtime.h>
#include <hip/hip_bf16.h>

#define NEG_SLOPE 0.2f

typedef _Float16 half8 __attribute__((ext_vector_type(8)));
typedef float floatx4 __attribute__((ext_vector_type(4)));

// ---------------------------------------------------------------- CSR build
__global__ void k_hist(const int* __restrict__ dst, int E, int n, int* __restrict__ deg) {
    int e = blockIdx.x * blockDim.x + threadIdx.x;
    int ET = E + n;
    if (e >= ET) return;
    int d = (e < E) ? dst[e] : (e - E);   // self-loops appended
    atomicAdd(&deg[d], 1);
}

__global__ void k_scan(const int* __restrict__ deg, int* __restrict__ rowptr,
                       int* __restrict__ cursor, int n) {
    __shared__ int part[256];
    int t = threadIdx.x;
    int chunk = (n + 255) / 256;
    int s0 = t * chunk, s1 = min(s0 + chunk, n);
    int s = 0;
    for (int i = s0; i < s1; ++i) s += deg[i];
    part[t] = s;
    __syncthreads();
    for (int off = 1; off < 256; off <<= 1) {
        int v = (t >= off) ? part[t - off] : 0;
        __syncthreads();
        part[t] += v;
        __syncthreads();
    }
    int run = (t == 0) ? 0 : part[t - 1];
    for (int i = s0; i < s1; ++i) { rowptr[i] = run; cursor[i] = run; run += deg[i]; }
    if (t == 255) rowptr[n] = run;
}

__global__ void k_scatter(const int* __restrict__ src, const int* __restrict__ dst,
                          int E, int n, int* __restrict__ cursor, int* __restrict__ csr_src) {
    int e = blockIdx.x * blockDim.x + threadIdx.x;
    int ET = E + n;
    if (e >= ET) return;
    int s = (e < E) ? src[e] : (e - E);
    int d = (e < E) ? dst[e] : (e - E);
    int pos = atomicAdd(&cursor[d], 1);
    csr_src[pos] = s;
}

// ------------------------------------------------------------- conversions
__global__ void k_f2h8(const float* __restrict__ in, _Float16* __restrict__ out, int n8) {
    int i = blockIdx.x * 256 + threadIdx.x;
    if (i >= n8) return;
    const float4* p = (const float4*)in + (size_t)i * 2;
    float4 a = p[0], b = p[1];
    _Float16 h[8] = {(_Float16)a.x, (_Float16)a.y, (_Float16)a.z, (_Float16)a.w,
                     (_Float16)b.x, (_Float16)b.y, (_Float16)b.z, (_Float16)b.w};
    *(uint4*)(out + (size_t)i * 8) = *(const uint4*)h;
}

// W[R][C] fp32 -> Wt[C][R] fp16 (output-coalesced; input L2-cached, tiny)
__global__ void k_transpose_h(const float* __restrict__ W, _Float16* __restrict__ Wt,
                              int R, int C) {
    int i = blockIdx.x * 256 + threadIdx.x;
    if (i >= R * C) return;
    int c = i / R, r = i % R;
    Wt[i] = (_Float16)W[(size_t)r * C + c];
}

// ------------------------------------------------------------ fp16 MFMA GEMM
// C[M,N] = A[M,K] @ Bt[N,K]^T. 128x128 tile, BK=32, 4 waves, 4x4 16x16 frags.
// LDS layout per matrix: [koct(4)][row(128)][8 halves] => consecutive lanes
// read consecutive rows (conflict-free b128), and global_load_lds dest is
// linear base + lane*16.
__device__ __forceinline__ void gload_lds16(const _Float16* g, _Float16* l) {
    __builtin_amdgcn_global_load_lds((const __attribute__((address_space(1))) void*)g,
                                     (__attribute__((address_space(3))) void*)l,
                                     16, 0, 0);
}

__global__ __launch_bounds__(256) void k_hgemm(const _Float16* __restrict__ A,
                                               const _Float16* __restrict__ Bt,
                                               float* __restrict__ C,
                                               int M, int N, int K) {
    __shared__ _Float16 lds[2 * 8192];       // [buf][A:4096|B:4096] elems (32KB)
    int t = threadIdx.x;
    int lane = t & 63, w = t >> 6;
    int wr = w >> 1, wc = w & 1;
    int lrow = lane & 15, lko = lane >> 4;
    int row0 = blockIdx.y * 128, col0 = blockIdx.x * 128;

    int sr = t & 127;                        // staging row
    int sko = t >> 7;                        // staging k-octet base (0/1)
    int agr = row0 + sr; if (agr >= M) agr = M - 1;
    const _Float16* aRow = A + (size_t)agr * K;
    const _Float16* bRow = Bt + (size_t)(col0 + sr) * K;

    floatx4 acc[4][4] = {};

    int nk = K >> 5;
    // prologue stage: buf 0, kt = 0
#pragma unroll
    for (int s = 0; s < 2; ++s) {
        int ko = s * 2 + sko;
        gload_lds16(aRow + ko * 8, lds + s * 2048 + t * 8);
        gload_lds16(bRow + ko * 8, lds + 4096 + s * 2048 + t * 8);
    }
    __syncthreads();

    for (int ks = 0; ks < nk; ++ks) {
        int buf = ks & 1;
        if (ks + 1 < nk) {
            int kt = (ks + 1) << 5;
            _Float16* dstb = lds + (buf ^ 1) * 8192;
#pragma unroll
            for (int s = 0; s < 2; ++s) {
                int ko = s * 2 + sko;
                gload_lds16(aRow + kt + ko * 8, dstb + s * 2048 + t * 8);
                gload_lds16(bRow + kt + ko * 8, dstb + 4096 + s * 2048 + t * 8);
            }
        }
        const _Float16* base = lds + buf * 8192 + lko * 1024;
        half8 af[4], bf[4];
#pragma unroll
        for (int mi = 0; mi < 4; ++mi)
            af[mi] = *(const half8*)(base + (wr * 64 + mi * 16 + lrow) * 8);
#pragma unroll
        for (int ni = 0; ni < 4; ++ni)
            bf[ni] = *(const half8*)(base + 4096 + (wc * 64 + ni * 16 + lrow) * 8);
#pragma unroll
        for (int mi = 0; mi < 4; ++mi)
#pragma unroll
            for (int ni = 0; ni < 4; ++ni)
                acc[mi][ni] = __builtin_amdgcn_mfma_f32_16x16x32_f16(
                    af[mi], bf[ni], acc[mi][ni], 0, 0, 0);
        __syncthreads();
    }

#pragma unroll
    for (int mi = 0; mi < 4; ++mi) {
        int rb = row0 + wr * 64 + mi * 16 + lko * 4;
#pragma unroll
        for (int ni = 0; ni < 4; ++ni) {
            int col = col0 + wc * 64 + ni * 16 + lrow;
#pragma unroll
            for (int j = 0; j < 4; ++j) {
                int row = rb + j;
                if (row < M) C[(size_t)row * N + col] = acc[mi][ni][j];
            }
        }
    }
}

// ------------------------------------------------------- attention logit dots
template <int H, int C>
__global__ void k_att(const float* __restrict__ h, const float* __restrict__ as,
                      const float* __restrict__ ad, float* __restrict__ al_s,
                      float* __restrict__ al_d, int n) {
    int wave = (blockIdx.x * blockDim.x + threadIdx.x) >> 6;
    int lane = threadIdx.x & 63;
    if (wave >= n * H) return;
    int node = wave / H, hh = wave % H;
    const float* hp = h + (size_t)node * H * C + hh * C;
    float aS = 0.f, aD = 0.f;
    for (int c = lane; c < C; c += 64) {
        float v = hp[c];
        aS += v * as[hh * C + c];
        aD += v * ad[hh * C + c];
    }
#pragma unroll
    for (int off = 32; off > 0; off >>= 1) {
        aS += __shfl_down(aS, off);
        aD += __shfl_down(aD, off);
    }
    if (lane == 0) { al_s[wave] = aS; al_d[wave] = aD; }
}

// ----------------------------------------------- per-node softmax + aggregate
template <int H, int C, typename OutT>
__global__ __launch_bounds__(256) void k_agg(const float* __restrict__ h,
                                             const float* __restrict__ al_s,
                                             const float* __restrict__ al_d,
                                             const int* __restrict__ rowptr,
                                             const int* __restrict__ csr_src,
                                             const float* __restrict__ bias,
                                             OutT* __restrict__ out) {
    constexpr int HC = H * C;
    constexpr int PT = (HC + 255) / 256;
    constexpr int CHUNK = 128;
    int node = blockIdx.x, t = threadIdx.x;
    int beg = rowptr[node], end = rowptr[node + 1];

    __shared__ float s_red[256];
    __shared__ float s_m[H], s_inv[H];
    __shared__ float s_alpha[CHUNK * H];
    __shared__ int s_src[CHUNK];

    float ald[H];
#pragma unroll
    for (int hh = 0; hh < H; ++hh) ald[hh] = al_d[node * H + hh];

    float mx[H];
#pragma unroll
    for (int hh = 0; hh < H; ++hh) mx[hh] = -1e30f;
    for (int i = beg + t; i < end; i += 256) {
        int s = csr_src[i];
#pragma unroll
        for (int hh = 0; hh < H; ++hh) {
            float e = al_s[s * H + hh] + ald[hh];
            e = e > 0.f ? e : NEG_SLOPE * e;
            mx[hh] = fmaxf(mx[hh], e);
        }
    }
#pragma unroll
    for (int hh = 0; hh < H; ++hh) {
        s_red[t] = mx[hh]; __syncthreads();
        for (int off = 128; off > 0; off >>= 1) {
            if (t < off) s_red[t] = fmaxf(s_red[t], s_red[t + off]);
            __syncthreads();
        }
        if (t == 0) s_m[hh] = s_red[0];
        __syncthreads();
    }

    float sm[H];
#pragma unroll
    for (int hh = 0; hh < H; ++hh) sm[hh] = 0.f;
    for (int i = beg + t; i < end; i += 256) {
        int s = csr_src[i];
#pragma unroll
        for (int hh = 0; hh < H; ++hh) {
            float e = al_s[s * H + hh] + ald[hh];
            e = e > 0.f ? e : NEG_SLOPE * e;
            sm[hh] += __expf(e - s_m[hh]);
        }
    }
#pragma unroll
    for (int hh = 0; hh < H; ++hh) {
        s_red[t] = sm[hh]; __syncthreads();
        for (int off = 128; off > 0; off >>= 1) {
            if (t < off) s_red[t] += s_red[t + off];
            __syncthreads();
        }
        if (t == 0) s_inv[hh] = 1.f / s_red[0];
        __syncthreads();
    }

    int hd[PT];
#pragma unroll
    for (int k = 0; k < PT; ++k) hd[k] = (t + k * 256) / C;
    float acc[PT];
#pragma unroll
    for (int k = 0; k < PT; ++k) acc[k] = 0.f;

    for (int cs = beg; cs < end; cs += CHUNK) {
        int cnt = min(CHUNK, end - cs);
        __syncthreads();
        for (int i = t; i < cnt; i += 256) {
            int s = csr_src[cs + i];
            s_src[i] = s;
#pragma unroll
            for (int hh = 0; hh < H; ++hh) {
                float e = al_s[s * H + hh] + ald[hh];
                e = e > 0.f ? e : NEG_SLOPE * e;
                s_alpha[i * H + hh] = __expf(e - s_m[hh]) * s_inv[hh];
            }
        }
        __syncthreads();
        for (int j = 0; j < cnt; ++j) {
            const float* hrow = h + (size_t)s_src[j] * HC;
#pragma unroll
            for (int k = 0; k < PT; ++k) {
                int ch = t + k * 256;
                if (HC % 256 == 0 || ch < HC)
                    acc[k] = fmaf(s_alpha[j * H + hd[k]], hrow[ch], acc[k]);
            }
        }
    }

#pragma unroll
    for (int k = 0; k < PT; ++k) {
        int ch = t + k * 256;
        if (HC % 256 == 0 || ch < HC) {
            float v = acc[k] + bias[ch];
            out[(size_t)node * HC + ch] = (OutT)(v > 0.f ? v : 0.f);
        }
    }
}

// ---------------------------------------------------------------------- host
extern "C" void kernel_launch(void* const* d_in, const int* in_sizes, int n_in,
                              void* d_out, int out_size, void* d_ws, size_t ws_size,
                              hipStream_t stream) {
    const float* x   = (const float*)d_in[0];
    const int*   ei  = (const int*)d_in[1];
    const float* W1  = (const float*)d_in[2];
    const float* as1 = (const float*)d_in[3];
    const float* ad1 = (const float*)d_in[4];
    const float* b1  = (const float*)d_in[5];
    const float* W2  = (const float*)d_in[6];
    const float* as2 = (const float*)d_in[7];
    const float* ad2 = (const float*)d_in[8];
    const float* b2  = (const float*)d_in[9];
    float* out = (float*)d_out;

    const int N  = in_sizes[0] / 128;   // 20000
    const int E  = in_sizes[1] / 2;     // 320000
    const int ET = E + N;
    const int* src = ei;
    const int* dst = ei + E;

    char* ws = (char*)d_ws;
    size_t off = 0;
    auto alloc = [&](size_t bytes) {
        void* p = ws + off;
        off = (off + bytes + 255) & ~(size_t)255;
        return p;
    };
    float*    h1   = (float*)alloc((size_t)N * 768 * 4);
    float*    h2   = (float*)alloc((size_t)N * 384 * 4);
    _Float16* xh   = (_Float16*)alloc((size_t)N * 128 * 2);
    _Float16* x2h  = (_Float16*)alloc((size_t)N * 768 * 2);
    _Float16* w1t  = (_Float16*)alloc((size_t)768 * 128 * 2);
    _Float16* w2t  = (_Float16*)alloc((size_t)384 * 768 * 2);
    float* alS1 = (float*)alloc((size_t)N * 3 * 4);
    float* alD1 = (float*)alloc((size_t)N * 3 * 4);
    float* alS2 = (float*)alloc((size_t)N * 4);
    float* alD2 = (float*)alloc((size_t)N * 4);
    int* deg    = (int*)alloc((size_t)N * 4);
    int* rowptr = (int*)alloc((size_t)(N + 1) * 4);
    int* cursor = (int*)alloc((size_t)N * 4);
    int* csrs   = (int*)alloc((size_t)ET * 4);

    // CSR by destination (shared by both layers)
    hipMemsetAsync(deg, 0, (size_t)N * 4, stream);
    k_hist<<<(ET + 255) / 256, 256, 0, stream>>>(dst, E, N, deg);
    k_scan<<<1, 256, 0, stream>>>(deg, rowptr, cursor, N);
    k_scatter<<<(ET + 255) / 256, 256, 0, stream>>>(src, dst, E, N, cursor, csrs);

    // operand prep (fp16)
    int n8 = N * 128 / 8;
    k_f2h8<<<(n8 + 255) / 256, 256, 0, stream>>>(x, xh, n8);
    k_transpose_h<<<(128 * 768 + 255) / 256, 256, 0, stream>>>(W1, w1t, 128, 768);
    k_transpose_h<<<(768 * 384 + 255) / 256, 256, 0, stream>>>(W2, w2t, 768, 384);

    // layer 1
    dim3 g1(768 / 128, (N + 127) / 128);
    k_hgemm<<<g1, 256, 0, stream>>>(xh, w1t, h1, N, 768, 128);
    k_att<3, 256><<<(N * 3 + 3) / 4, 256, 0, stream>>>(h1, as1, ad1, alS1, alD1, N);
    k_agg<3, 256, _Float16><<<N, 256, 0, stream>>>(h1, alS1, alD1, rowptr, csrs, b1, x2h);

    // layer 2
    dim3 g2(384 / 128, (N + 127) / 128);
    k_hgemm<<<g2, 256, 0, stream>>>(x2h, w2t, h2, N, 384, 768);
    k_att<1, 384><<<(N + 3) / 4, 256, 0, stream>>>(h2, as2, ad2, alS2, alD2, N);
    k_agg<1, 384, float><<<N, 256, 0, stream>>>(h2, alS2, alD2, rowptr, csrs, b2, out);
}

// Round 3
// 370.077 us; speedup vs baseline: 1.7489x; 1.3094x over previous
//
#include <hip/hip_runtime.h>
#include <hip/hip_bf16.h>

#define NEG_SLOPE 0.2f

typedef _Float16 half8 __attribute__((ext_vector_type(8)));
typedef float floatx4 __attribute__((ext_vector_type(4)));

// ---------------------------------------------------------------- CSR build
__global__ void k_hist(const int* __restrict__ dst, int E, int n, int* __restrict__ deg) {
    int e = blockIdx.x * blockDim.x + threadIdx.x;
    int ET = E + n;
    if (e >= ET) return;
    int d = (e < E) ? dst[e] : (e - E);   // self-loops appended
    atomicAdd(&deg[d], 1);
}

__global__ void k_scan(const int* __restrict__ deg, int* __restrict__ rowptr,
                       int* __restrict__ cursor, int n) {
    __shared__ int part[256];
    int t = threadIdx.x;
    int chunk = (n + 255) / 256;
    int s0 = t * chunk, s1 = min(s0 + chunk, n);
    int s = 0;
    for (int i = s0; i < s1; ++i) s += deg[i];
    part[t] = s;
    __syncthreads();
    for (int off = 1; off < 256; off <<= 1) {
        int v = (t >= off) ? part[t - off] : 0;
        __syncthreads();
        part[t] += v;
        __syncthreads();
    }
    int run = (t == 0) ? 0 : part[t - 1];
    for (int i = s0; i < s1; ++i) { rowptr[i] = run; cursor[i] = run; run += deg[i]; }
    if (t == 255) rowptr[n] = run;
}

__global__ void k_scatter(const int* __restrict__ src, const int* __restrict__ dst,
                          int E, int n, int* __restrict__ cursor, int* __restrict__ csr_src) {
    int e = blockIdx.x * blockDim.x + threadIdx.x;
    int ET = E + n;
    if (e >= ET) return;
    int s = (e < E) ? src[e] : (e - E);
    int d = (e < E) ? dst[e] : (e - E);
    int pos = atomicAdd(&cursor[d], 1);
    csr_src[pos] = s;
}

// ------------------------------------------------------------- conversions
__global__ void k_f2h8(const float* __restrict__ in, _Float16* __restrict__ out, int n8) {
    int i = blockIdx.x * 256 + threadIdx.x;
    if (i >= n8) return;
    const float4* p = (const float4*)in + (size_t)i * 2;
    float4 a = p[0], b = p[1];
    _Float16 h[8] = {(_Float16)a.x, (_Float16)a.y, (_Float16)a.z, (_Float16)a.w,
                     (_Float16)b.x, (_Float16)b.y, (_Float16)b.z, (_Float16)b.w};
    *(uint4*)(out + (size_t)i * 8) = *(const uint4*)h;
}

// W[R][C] fp32 -> Wt[C][R] fp16 (output-coalesced; input L2-cached, tiny)
__global__ void k_transpose_h(const float* __restrict__ W, _Float16* __restrict__ Wt,
                              int R, int C) {
    int i = blockIdx.x * 256 + threadIdx.x;
    if (i >= R * C) return;
    int c = i / R, r = i % R;
    Wt[i] = (_Float16)W[(size_t)r * C + c];
}

// ------------------------------------------------------------ fp16 MFMA GEMM
// C[M,N] = A[M,K] @ Bt[N,K]^T. 128x128 tile, BK=32, 4 waves, 4x4 16x16 frags.
__device__ __forceinline__ void gload_lds16(const _Float16* g, _Float16* l) {
    __builtin_amdgcn_global_load_lds((const __attribute__((address_space(1))) void*)g,
                                     (__attribute__((address_space(3))) void*)l,
                                     16, 0, 0);
}

template <typename OutT>
__global__ __launch_bounds__(256) void k_hgemm(const _Float16* __restrict__ A,
                                               const _Float16* __restrict__ Bt,
                                               OutT* __restrict__ C,
                                               int M, int N, int K) {
    __shared__ _Float16 lds[2 * 8192];       // [buf][A:4096|B:4096] elems (32KB)
    int t = threadIdx.x;
    int lane = t & 63, w = t >> 6;
    int wr = w >> 1, wc = w & 1;
    int lrow = lane & 15, lko = lane >> 4;
    int row0 = blockIdx.y * 128, col0 = blockIdx.x * 128;

    int sr = t & 127;                        // staging row
    int sko = t >> 7;                        // staging k-octet base (0/1)
    int agr = row0 + sr; if (agr >= M) agr = M - 1;
    const _Float16* aRow = A + (size_t)agr * K;
    const _Float16* bRow = Bt + (size_t)(col0 + sr) * K;

    floatx4 acc[4][4] = {};

    int nk = K >> 5;
#pragma unroll
    for (int s = 0; s < 2; ++s) {
        int ko = s * 2 + sko;
        gload_lds16(aRow + ko * 8, lds + s * 2048 + t * 8);
        gload_lds16(bRow + ko * 8, lds + 4096 + s * 2048 + t * 8);
    }
    __syncthreads();

    for (int ks = 0; ks < nk; ++ks) {
        int buf = ks & 1;
        if (ks + 1 < nk) {
            int kt = (ks + 1) << 5;
            _Float16* dstb = lds + (buf ^ 1) * 8192;
#pragma unroll
            for (int s = 0; s < 2; ++s) {
                int ko = s * 2 + sko;
                gload_lds16(aRow + kt + ko * 8, dstb + s * 2048 + t * 8);
                gload_lds16(bRow + kt + ko * 8, dstb + 4096 + s * 2048 + t * 8);
            }
        }
        const _Float16* base = lds + buf * 8192 + lko * 1024;
        half8 af[4], bf[4];
#pragma unroll
        for (int mi = 0; mi < 4; ++mi)
            af[mi] = *(const half8*)(base + (wr * 64 + mi * 16 + lrow) * 8);
#pragma unroll
        for (int ni = 0; ni < 4; ++ni)
            bf[ni] = *(const half8*)(base + 4096 + (wc * 64 + ni * 16 + lrow) * 8);
#pragma unroll
        for (int mi = 0; mi < 4; ++mi)
#pragma unroll
            for (int ni = 0; ni < 4; ++ni)
                acc[mi][ni] = __builtin_amdgcn_mfma_f32_16x16x32_f16(
                    af[mi], bf[ni], acc[mi][ni], 0, 0, 0);
        __syncthreads();
    }

#pragma unroll
    for (int mi = 0; mi < 4; ++mi) {
        int rb = row0 + wr * 64 + mi * 16 + lko * 4;
#pragma unroll
        for (int ni = 0; ni < 4; ++ni) {
            int col = col0 + wc * 64 + ni * 16 + lrow;
#pragma unroll
            for (int j = 0; j < 4; ++j) {
                int row = rb + j;
                if (row < M) C[(size_t)row * N + col] = (OutT)acc[mi][ni][j];
            }
        }
    }
}

// ------------------------------------------------------- attention logit dots
template <int H, int C>
__global__ void k_att(const _Float16* __restrict__ h, const float* __restrict__ as,
                      const float* __restrict__ ad, float* __restrict__ al_s,
                      float* __restrict__ al_d, int n) {
    int wave = (blockIdx.x * blockDim.x + threadIdx.x) >> 6;
    int lane = threadIdx.x & 63;
    if (wave >= n * H) return;
    int node = wave / H, hh = wave % H;
    const _Float16* hp = h + (size_t)node * H * C + hh * C;
    float aS = 0.f, aD = 0.f;
    for (int c = lane; c < C; c += 64) {
        float v = (float)hp[c];
        aS += v * as[hh * C + c];
        aD += v * ad[hh * C + c];
    }
#pragma unroll
    for (int off = 32; off > 0; off >>= 1) {
        aS += __shfl_down(aS, off);
        aD += __shfl_down(aD, off);
    }
    if (lane == 0) { al_s[wave] = aS; al_d[wave] = aD; }
}

// ----------------------------------------------- per-node softmax + aggregate
template <int H, int C, typename OutT>
__global__ __launch_bounds__(256) void k_agg(const _Float16* __restrict__ h,
                                             const float* __restrict__ al_s,
                                             const float* __restrict__ al_d,
                                             const int* __restrict__ rowptr,
                                             const int* __restrict__ csr_src,
                                             const float* __restrict__ bias,
                                             OutT* __restrict__ out) {
    constexpr int HC = H * C;
    constexpr int PT = (HC + 255) / 256;
    constexpr int CHUNK = 128;
    int node = blockIdx.x, t = threadIdx.x;
    int beg = rowptr[node], end = rowptr[node + 1];

    __shared__ float s_red[256];
    __shared__ float s_m[H], s_inv[H];
    __shared__ float s_alpha[CHUNK * H];
    __shared__ int s_src[CHUNK];

    float ald[H];
#pragma unroll
    for (int hh = 0; hh < H; ++hh) ald[hh] = al_d[node * H + hh];

    // pass 1: per-head max of leaky_relu logits
    float mx[H];
#pragma unroll
    for (int hh = 0; hh < H; ++hh) mx[hh] = -1e30f;
    for (int i = beg + t; i < end; i += 256) {
        int s = csr_src[i];
#pragma unroll
        for (int hh = 0; hh < H; ++hh) {
            float e = al_s[s * H + hh] + ald[hh];
            e = e > 0.f ? e : NEG_SLOPE * e;
            mx[hh] = fmaxf(mx[hh], e);
        }
    }
#pragma unroll
    for (int hh = 0; hh < H; ++hh) {
        s_red[t] = mx[hh]; __syncthreads();
        for (int off = 128; off > 0; off >>= 1) {
            if (t < off) s_red[t] = fmaxf(s_red[t], s_red[t + off]);
            __syncthreads();
        }
        if (t == 0) s_m[hh] = s_red[0];
        __syncthreads();
    }

    // pass 2: denom
    float sm[H];
#pragma unroll
    for (int hh = 0; hh < H; ++hh) sm[hh] = 0.f;
    for (int i = beg + t; i < end; i += 256) {
        int s = csr_src[i];
#pragma unroll
        for (int hh = 0; hh < H; ++hh) {
            float e = al_s[s * H + hh] + ald[hh];
            e = e > 0.f ? e : NEG_SLOPE * e;
            sm[hh] += __expf(e - s_m[hh]);
        }
    }
#pragma unroll
    for (int hh = 0; hh < H; ++hh) {
        s_red[t] = sm[hh]; __syncthreads();
        for (int off = 128; off > 0; off >>= 1) {
            if (t < off) s_red[t] += s_red[t + off];
            __syncthreads();
        }
        if (t == 0) s_inv[hh] = 1.f / s_red[0];
        __syncthreads();
    }

    // pass 3: chunked weighted aggregation, 4x edge-unrolled for load depth
    int hd[PT];
#pragma unroll
    for (int k = 0; k < PT; ++k) hd[k] = (t + k * 256) / C;
    float acc[PT];
#pragma unroll
    for (int k = 0; k < PT; ++k) acc[k] = 0.f;

    for (int cs = beg; cs < end; cs += CHUNK) {
        int cnt = min(CHUNK, end - cs);
        __syncthreads();
        for (int i = t; i < cnt; i += 256) {
            int s = csr_src[cs + i];
            s_src[i] = s;
#pragma unroll
            for (int hh = 0; hh < H; ++hh) {
                float e = al_s[s * H + hh] + ald[hh];
                e = e > 0.f ? e : NEG_SLOPE * e;
                s_alpha[i * H + hh] = __expf(e - s_m[hh]) * s_inv[hh];
            }
        }
        __syncthreads();
        int j = 0;
        for (; j + 4 <= cnt; j += 4) {
            const _Float16* r0 = h + (size_t)s_src[j + 0] * HC;
            const _Float16* r1 = h + (size_t)s_src[j + 1] * HC;
            const _Float16* r2 = h + (size_t)s_src[j + 2] * HC;
            const _Float16* r3 = h + (size_t)s_src[j + 3] * HC;
            float v0[PT], v1[PT], v2[PT], v3[PT];
#pragma unroll
            for (int k = 0; k < PT; ++k) {
                int ch = t + k * 256;
                if (HC % 256 == 0 || ch < HC) {
                    v0[k] = (float)r0[ch]; v1[k] = (float)r1[ch];
                    v2[k] = (float)r2[ch]; v3[k] = (float)r3[ch];
                }
            }
#pragma unroll
            for (int k = 0; k < PT; ++k) {
                int ch = t + k * 256;
                if (HC % 256 == 0 || ch < HC) {
                    acc[k] = fmaf(s_alpha[(j + 0) * H + hd[k]], v0[k], acc[k]);
                    acc[k] = fmaf(s_alpha[(j + 1) * H + hd[k]], v1[k], acc[k]);
                    acc[k] = fmaf(s_alpha[(j + 2) * H + hd[k]], v2[k], acc[k]);
                    acc[k] = fmaf(s_alpha[(j + 3) * H + hd[k]], v3[k], acc[k]);
                }
            }
        }
        for (; j < cnt; ++j) {
            const _Float16* hrow = h + (size_t)s_src[j] * HC;
#pragma unroll
            for (int k = 0; k < PT; ++k) {
                int ch = t + k * 256;
                if (HC % 256 == 0 || ch < HC)
                    acc[k] = fmaf(s_alpha[j * H + hd[k]], (float)hrow[ch], acc[k]);
            }
        }
    }

#pragma unroll
    for (int k = 0; k < PT; ++k) {
        int ch = t + k * 256;
        if (HC % 256 == 0 || ch < HC) {
            float v = acc[k] + bias[ch];
            out[(size_t)node * HC + ch] = (OutT)(v > 0.f ? v : 0.f);
        }
    }
}

// ---------------------------------------------------------------------- host
extern "C" void kernel_launch(void* const* d_in, const int* in_sizes, int n_in,
                              void* d_out, int out_size, void* d_ws, size_t ws_size,
                              hipStream_t stream) {
    const float* x   = (const float*)d_in[0];
    const int*   ei  = (const int*)d_in[1];
    const float* W1  = (const float*)d_in[2];
    const float* as1 = (const float*)d_in[3];
    const float* ad1 = (const float*)d_in[4];
    const float* b1  = (const float*)d_in[5];
    const float* W2  = (const float*)d_in[6];
    const float* as2 = (const float*)d_in[7];
    const float* ad2 = (const float*)d_in[8];
    const float* b2  = (const float*)d_in[9];
    float* out = (float*)d_out;

    const int N  = in_sizes[0] / 128;   // 20000
    const int E  = in_sizes[1] / 2;     // 320000
    const int ET = E + N;
    const int* src = ei;
    const int* dst = ei + E;

    char* ws = (char*)d_ws;
    size_t off = 0;
    auto alloc = [&](size_t bytes) {
        void* p = ws + off;
        off = (off + bytes + 255) & ~(size_t)255;
        return p;
    };
    _Float16* h1   = (_Float16*)alloc((size_t)N * 768 * 2);
    _Float16* h2   = (_Float16*)alloc((size_t)N * 384 * 2);
    _Float16* xh   = (_Float16*)alloc((size_t)N * 128 * 2);
    _Float16* x2h  = (_Float16*)alloc((size_t)N * 768 * 2);
    _Float16* w1t  = (_Float16*)alloc((size_t)768 * 128 * 2);
    _Float16* w2t  = (_Float16*)alloc((size_t)384 * 768 * 2);
    float* alS1 = (float*)alloc((size_t)N * 3 * 4);
    float* alD1 = (float*)alloc((size_t)N * 3 * 4);
    float* alS2 = (float*)alloc((size_t)N * 4);
    float* alD2 = (float*)alloc((size_t)N * 4);
    int* deg    = (int*)alloc((size_t)N * 4);
    int* rowptr = (int*)alloc((size_t)(N + 1) * 4);
    int* cursor = (int*)alloc((size_t)N * 4);
    int* csrs   = (int*)alloc((size_t)ET * 4);

    // CSR by destination (shared by both layers)
    hipMemsetAsync(deg, 0, (size_t)N * 4, stream);
    k_hist<<<(ET + 255) / 256, 256, 0, stream>>>(dst, E, N, deg);
    k_scan<<<1, 256, 0, stream>>>(deg, rowptr, cursor, N);
    k_scatter<<<(ET + 255) / 256, 256, 0, stream>>>(src, dst, E, N, cursor, csrs);

    // operand prep (fp16)
    int n8 = N * 128 / 8;
    k_f2h8<<<(n8 + 255) / 256, 256, 0, stream>>>(x, xh, n8);
    k_transpose_h<<<(128 * 768 + 255) / 256, 256, 0, stream>>>(W1, w1t, 128, 768);
    k_transpose_h<<<(768 * 384 + 255) / 256, 256, 0, stream>>>(W2, w2t, 768, 384);

    // layer 1
    dim3 g1(768 / 128, (N + 127) / 128);
    k_hgemm<_Float16><<<g1, 256, 0, stream>>>(xh, w1t, h1, N, 768, 128);
    k_att<3, 256><<<(N * 3 + 3) / 4, 256, 0, stream>>>(h1, as1, ad1, alS1, alD1, N);
    k_agg<3, 256, _Float16><<<N, 256, 0, stream>>>(h1, alS1, alD1, rowptr, csrs, b1, x2h);

    // layer 2
    dim3 g2(384 / 128, (N + 127) / 128);
    k_hgemm<_Float16><<<g2, 256, 0, stream>>>(x2h, w2t, h2, N, 384, 768);
    k_att<1, 384><<<(N + 3) / 4, 256, 0, stream>>>(h2, as2, ad2, alS2, alD2, N);
    k_agg<1, 384, float><<<N, 256, 0, stream>>>(h2, alS2, alD2, rowptr, csrs, b2, out);
}

// Round 4
// 283.700 us; speedup vs baseline: 2.2814x; 1.3045x over previous
//
#include <hip/hip_runtime.h>
#include <hip/hip_bf16.h>

#define NEG_SLOPE 0.2f

typedef _Float16 half8 __attribute__((ext_vector_type(8)));
typedef _Float16 half4v __attribute__((ext_vector_type(4)));
typedef _Float16 half2v __attribute__((ext_vector_type(2)));
typedef float floatx4 __attribute__((ext_vector_type(4)));
typedef float floatx2 __attribute__((ext_vector_type(2)));

// ---------------------------------------------------------------- CSR build
__global__ void k_hist(const int* __restrict__ dst, int E, int n, int* __restrict__ deg) {
    int e = blockIdx.x * blockDim.x + threadIdx.x;
    int ET = E + n;
    if (e >= ET) return;
    int d = (e < E) ? dst[e] : (e - E);   // self-loops appended
    atomicAdd(&deg[d], 1);
}

__global__ void k_scan(const int* __restrict__ deg, int* __restrict__ rowptr,
                       int* __restrict__ cursor, int n) {
    __shared__ int part[256];
    int t = threadIdx.x;
    int chunk = (n + 255) / 256;
    int s0 = t * chunk, s1 = min(s0 + chunk, n);
    int s = 0;
    for (int i = s0; i < s1; ++i) s += deg[i];
    part[t] = s;
    __syncthreads();
    for (int off = 1; off < 256; off <<= 1) {
        int v = (t >= off) ? part[t - off] : 0;
        __syncthreads();
        part[t] += v;
        __syncthreads();
    }
    int run = (t == 0) ? 0 : part[t - 1];
    for (int i = s0; i < s1; ++i) { rowptr[i] = run; cursor[i] = run; run += deg[i]; }
    if (t == 255) rowptr[n] = run;
}

__global__ void k_scatter(const int* __restrict__ src, const int* __restrict__ dst,
                          int E, int n, int* __restrict__ cursor, int* __restrict__ csr_src) {
    int e = blockIdx.x * blockDim.x + threadIdx.x;
    int ET = E + n;
    if (e >= ET) return;
    int s = (e < E) ? src[e] : (e - E);
    int d = (e < E) ? dst[e] : (e - E);
    int pos = atomicAdd(&cursor[d], 1);
    csr_src[pos] = s;
}

// ------------------------------------------------------------- conversions
__global__ void k_f2h8(const float* __restrict__ in, _Float16* __restrict__ out, int n8) {
    int i = blockIdx.x * 256 + threadIdx.x;
    if (i >= n8) return;
    const float4* p = (const float4*)in + (size_t)i * 2;
    float4 a = p[0], b = p[1];
    _Float16 h[8] = {(_Float16)a.x, (_Float16)a.y, (_Float16)a.z, (_Float16)a.w,
                     (_Float16)b.x, (_Float16)b.y, (_Float16)b.z, (_Float16)b.w};
    *(uint4*)(out + (size_t)i * 8) = *(const uint4*)h;
}

// W[R][C] fp32 -> Wt[C][R] fp16
__global__ void k_transpose_h(const float* __restrict__ W, _Float16* __restrict__ Wt,
                              int R, int C) {
    int i = blockIdx.x * 256 + threadIdx.x;
    if (i >= R * C) return;
    int c = i / R, r = i % R;
    Wt[i] = (_Float16)W[(size_t)r * C + c];
}

// ------------------------------------------------------------ fp16 MFMA GEMM
__device__ __forceinline__ void gload_lds16(const _Float16* g, _Float16* l) {
    __builtin_amdgcn_global_load_lds((const __attribute__((address_space(1))) void*)g,
                                     (__attribute__((address_space(3))) void*)l,
                                     16, 0, 0);
}

template <typename OutT>
__global__ __launch_bounds__(256) void k_hgemm(const _Float16* __restrict__ A,
                                               const _Float16* __restrict__ Bt,
                                               OutT* __restrict__ C,
                                               int M, int N, int K) {
    __shared__ _Float16 lds[2 * 8192];       // [buf][A:4096|B:4096] elems (32KB)
    int t = threadIdx.x;
    int lane = t & 63, w = t >> 6;
    int wr = w >> 1, wc = w & 1;
    int lrow = lane & 15, lko = lane >> 4;
    int row0 = blockIdx.y * 128, col0 = blockIdx.x * 128;

    int sr = t & 127;
    int sko = t >> 7;
    int agr = row0 + sr; if (agr >= M) agr = M - 1;
    const _Float16* aRow = A + (size_t)agr * K;
    const _Float16* bRow = Bt + (size_t)(col0 + sr) * K;

    floatx4 acc[4][4] = {};

    int nk = K >> 5;
#pragma unroll
    for (int s = 0; s < 2; ++s) {
        int ko = s * 2 + sko;
        gload_lds16(aRow + ko * 8, lds + s * 2048 + t * 8);
        gload_lds16(bRow + ko * 8, lds + 4096 + s * 2048 + t * 8);
    }
    __syncthreads();

    for (int ks = 0; ks < nk; ++ks) {
        int buf = ks & 1;
        if (ks + 1 < nk) {
            int kt = (ks + 1) << 5;
            _Float16* dstb = lds + (buf ^ 1) * 8192;
#pragma unroll
            for (int s = 0; s < 2; ++s) {
                int ko = s * 2 + sko;
                gload_lds16(aRow + kt + ko * 8, dstb + s * 2048 + t * 8);
                gload_lds16(bRow + kt + ko * 8, dstb + 4096 + s * 2048 + t * 8);
            }
        }
        const _Float16* base = lds + buf * 8192 + lko * 1024;
        half8 af[4], bf[4];
#pragma unroll
        for (int mi = 0; mi < 4; ++mi)
            af[mi] = *(const half8*)(base + (wr * 64 + mi * 16 + lrow) * 8);
#pragma unroll
        for (int ni = 0; ni < 4; ++ni)
            bf[ni] = *(const half8*)(base + 4096 + (wc * 64 + ni * 16 + lrow) * 8);
#pragma unroll
        for (int mi = 0; mi < 4; ++mi)
#pragma unroll
            for (int ni = 0; ni < 4; ++ni)
                acc[mi][ni] = __builtin_amdgcn_mfma_f32_16x16x32_f16(
                    af[mi], bf[ni], acc[mi][ni], 0, 0, 0);
        __syncthreads();
    }

#pragma unroll
    for (int mi = 0; mi < 4; ++mi) {
        int rb = row0 + wr * 64 + mi * 16 + lko * 4;
#pragma unroll
        for (int ni = 0; ni < 4; ++ni) {
            int col = col0 + wc * 64 + ni * 16 + lrow;
#pragma unroll
            for (int j = 0; j < 4; ++j) {
                int row = rb + j;
                if (row < M) C[(size_t)row * N + col] = (OutT)acc[mi][ni][j];
            }
        }
    }
}

// ------------------------------------------------------- attention logit dots
// one wave per (node, head); vectorized 4-ch (+2-ch tail for C=384) loads
template <int H, int C>
__global__ __launch_bounds__(256) void k_att(const _Float16* __restrict__ h,
                      const float* __restrict__ as, const float* __restrict__ ad,
                      float* __restrict__ al_s, float* __restrict__ al_d, int n) {
    int wid = (blockIdx.x * blockDim.x + threadIdx.x) >> 6;
    int lane = threadIdx.x & 63;
    if (wid >= n * H) return;
    int node = wid / H, hh = wid % H;
    const _Float16* hp = h + (size_t)node * H * C + hh * C;
    const float* sp = as + hh * C;
    const float* dp = ad + hh * C;
    float aS, aD;
    {
        half4v v = *(const half4v*)(hp + lane * 4);
        float4 a = *(const float4*)(sp + lane * 4);
        float4 d = *(const float4*)(dp + lane * 4);
        float f0 = (float)v[0], f1 = (float)v[1], f2 = (float)v[2], f3 = (float)v[3];
        aS = f0 * a.x + f1 * a.y + f2 * a.z + f3 * a.w;
        aD = f0 * d.x + f1 * d.y + f2 * d.z + f3 * d.w;
    }
    if constexpr (C == 384) {
        half2v v = *(const half2v*)(hp + 256 + lane * 2);
        floatx2 a = *(const floatx2*)(sp + 256 + lane * 2);
        floatx2 d = *(const floatx2*)(dp + 256 + lane * 2);
        aS += (float)v[0] * a[0] + (float)v[1] * a[1];
        aD += (float)v[0] * d[0] + (float)v[1] * d[1];
    }
#pragma unroll
    for (int off = 32; off; off >>= 1) {
        aS += __shfl_xor(aS, off);
        aD += __shfl_xor(aD, off);
    }
    if (lane == 0) { al_s[wid] = aS; al_d[wid] = aD; }
}

// ----------------------------------------------- per-node softmax + aggregate
// ONE WAVE PER DST NODE. Lane owns CA contiguous channels (16B half8 for
// HC=768) + CB channels tail. In-wave butterfly softmax; per-edge src index
// and exp values broadcast from lane registers via __shfl. 2 VMEM/edge/wave.
template <int H, int C, typename OutT>
__global__ __launch_bounds__(256) void k_aggw(const _Float16* __restrict__ h,
                                              const float* __restrict__ al_s,
                                              const float* __restrict__ al_d,
                                              const int* __restrict__ rowptr,
                                              const int* __restrict__ csr_src,
                                              const float* __restrict__ bias,
                                              OutT* __restrict__ out, int n) {
    constexpr int HC = H * C;
    constexpr int CA = HC / 96;    // 8 (HC=768) or 4 (HC=384): chans in load A
    constexpr int CB = CA / 2;     // tail chans in load B
    int wid = (blockIdx.x * blockDim.x + threadIdx.x) >> 6;
    int lane = threadIdx.x & 63;
    if (wid >= n) return;
    int beg = rowptr[wid], end = rowptr[wid + 1];

    float ald[H];
#pragma unroll
    for (int hh = 0; hh < H; ++hh) ald[hh] = al_d[wid * H + hh];

    // pass 1: per-head max of leaky logits (lane-strided + butterfly)
    float m[H];
#pragma unroll
    for (int hh = 0; hh < H; ++hh) m[hh] = -1e30f;
    for (int base = beg; base < end; base += 64) {
        int i = base + lane;
        if (i < end) {
            int s = csr_src[i];
#pragma unroll
            for (int hh = 0; hh < H; ++hh) {
                float e = al_s[s * H + hh] + ald[hh];
                e = e > 0.f ? e : NEG_SLOPE * e;
                m[hh] = fmaxf(m[hh], e);
            }
        }
    }
#pragma unroll
    for (int hh = 0; hh < H; ++hh)
#pragma unroll
        for (int off = 32; off; off >>= 1) m[hh] = fmaxf(m[hh], __shfl_xor(m[hh], off));

    // pass 2: denominator
    float sm[H];
#pragma unroll
    for (int hh = 0; hh < H; ++hh) sm[hh] = 0.f;
    for (int base = beg; base < end; base += 64) {
        int i = base + lane;
        if (i < end) {
            int s = csr_src[i];
#pragma unroll
            for (int hh = 0; hh < H; ++hh) {
                float e = al_s[s * H + hh] + ald[hh];
                e = e > 0.f ? e : NEG_SLOPE * e;
                sm[hh] += __expf(e - m[hh]);
            }
        }
    }
    float inv[H];
#pragma unroll
    for (int hh = 0; hh < H; ++hh) {
#pragma unroll
        for (int off = 32; off; off >>= 1) sm[hh] += __shfl_xor(sm[hh], off);
        inv[hh] = 1.f / sm[hh];
    }

    // pass 3: gather + weighted accumulate
    float accA[CA] = {}, accB[CB] = {};
    for (int base = beg; base < end; base += 64) {
        int cnt = min(64, end - base);
        int i = base + lane;
        int sl = (i < end) ? csr_src[i] : 0;
        float ex[H];
#pragma unroll
        for (int hh = 0; hh < H; ++hh) {
            float e = al_s[sl * H + hh] + ald[hh];
            e = e > 0.f ? e : NEG_SLOPE * e;
            ex[hh] = (i < end) ? __expf(e - m[hh]) * inv[hh] : 0.f;
        }
        for (int j = 0; j < cnt; ++j) {
            int s = __shfl(sl, j);
            float aA, aB;
            if constexpr (H == 3) {
                float s0 = __shfl(ex[0], j);
                float s1 = __shfl(ex[1], j);
                float s2 = __shfl(ex[2], j);
                aA = (lane < 32) ? s0 : s1;   // load-A chans: lanes 0-31 head0, 32-63 head1
                aB = s2;                      // tail chans: head 2
            } else {
                aA = aB = __shfl(ex[0], j);
            }
            const _Float16* row = h + (size_t)s * HC;
            if constexpr (CA == 8) {
                half8 va = *(const half8*)(row + lane * 8);
                half4v vb = *(const half4v*)(row + 512 + lane * 4);
#pragma unroll
                for (int k = 0; k < 8; ++k) accA[k] = fmaf(aA, (float)va[k], accA[k]);
#pragma unroll
                for (int k = 0; k < 4; ++k) accB[k] = fmaf(aB, (float)vb[k], accB[k]);
            } else {
                half4v va = *(const half4v*)(row + lane * 4);
                half2v vb = *(const half2v*)(row + 256 + lane * 2);
#pragma unroll
                for (int k = 0; k < 4; ++k) accA[k] = fmaf(aA, (float)va[k], accA[k]);
#pragma unroll
                for (int k = 0; k < 2; ++k) accB[k] = fmaf(aB, (float)vb[k], accB[k]);
            }
        }
    }

    // epilogue: bias + relu, vectorized store
    size_t obase = (size_t)wid * HC;
    int cA0 = lane * CA, cB0 = 64 * CA + lane * CB;
    if constexpr (sizeof(OutT) == 2) {
        _Float16* op = (_Float16*)out;
        if constexpr (CA == 8) {
            half8 oa;
#pragma unroll
            for (int k = 0; k < 8; ++k) {
                float v = accA[k] + bias[cA0 + k];
                oa[k] = (_Float16)(v > 0.f ? v : 0.f);
            }
            *(half8*)(op + obase + cA0) = oa;
            half4v ob;
#pragma unroll
            for (int k = 0; k < 4; ++k) {
                float v = accB[k] + bias[cB0 + k];
                ob[k] = (_Float16)(v > 0.f ? v : 0.f);
            }
            *(half4v*)(op + obase + cB0) = ob;
        } else {
            half4v oa;
#pragma unroll
            for (int k = 0; k < 4; ++k) {
                float v = accA[k] + bias[cA0 + k];
                oa[k] = (_Float16)(v > 0.f ? v : 0.f);
            }
            *(half4v*)(op + obase + cA0) = oa;
            half2v ob;
#pragma unroll
            for (int k = 0; k < 2; ++k) {
                float v = accB[k] + bias[cB0 + k];
                ob[k] = (_Float16)(v > 0.f ? v : 0.f);
            }
            *(half2v*)(op + obase + cB0) = ob;
        }
    } else {
        float* op = (float*)out;
        if constexpr (CA == 4) {
            float4 oa;
            float t0 = accA[0] + bias[cA0 + 0]; oa.x = t0 > 0.f ? t0 : 0.f;
            float t1 = accA[1] + bias[cA0 + 1]; oa.y = t1 > 0.f ? t1 : 0.f;
            float t2 = accA[2] + bias[cA0 + 2]; oa.z = t2 > 0.f ? t2 : 0.f;
            float t3 = accA[3] + bias[cA0 + 3]; oa.w = t3 > 0.f ? t3 : 0.f;
            *(float4*)(op + obase + cA0) = oa;
            floatx2 ob;
            float u0 = accB[0] + bias[cB0 + 0]; ob[0] = u0 > 0.f ? u0 : 0.f;
            float u1 = accB[1] + bias[cB0 + 1]; ob[1] = u1 > 0.f ? u1 : 0.f;
            *(floatx2*)(op + obase + cB0) = ob;
        } else {
#pragma unroll
            for (int k = 0; k < CA; ++k) {
                float v = accA[k] + bias[cA0 + k];
                op[obase + cA0 + k] = v > 0.f ? v : 0.f;
            }
#pragma unroll
            for (int k = 0; k < CB; ++k) {
                float v = accB[k] + bias[cB0 + k];
                op[obase + cB0 + k] = v > 0.f ? v : 0.f;
            }
        }
    }
}

// ---------------------------------------------------------------------- host
extern "C" void kernel_launch(void* const* d_in, const int* in_sizes, int n_in,
                              void* d_out, int out_size, void* d_ws, size_t ws_size,
                              hipStream_t stream) {
    const float* x   = (const float*)d_in[0];
    const int*   ei  = (const int*)d_in[1];
    const float* W1  = (const float*)d_in[2];
    const float* as1 = (const float*)d_in[3];
    const float* ad1 = (const float*)d_in[4];
    const float* b1  = (const float*)d_in[5];
    const float* W2  = (const float*)d_in[6];
    const float* as2 = (const float*)d_in[7];
    const float* ad2 = (const float*)d_in[8];
    const float* b2  = (const float*)d_in[9];
    float* out = (float*)d_out;

    const int N  = in_sizes[0] / 128;   // 20000
    const int E  = in_sizes[1] / 2;     // 320000
    const int ET = E + N;
    const int* src = ei;
    const int* dst = ei + E;

    char* ws = (char*)d_ws;
    size_t off = 0;
    auto alloc = [&](size_t bytes) {
        void* p = ws + off;
        off = (off + bytes + 255) & ~(size_t)255;
        return p;
    };
    _Float16* h1   = (_Float16*)alloc((size_t)N * 768 * 2);
    _Float16* h2   = (_Float16*)alloc((size_t)N * 384 * 2);
    _Float16* xh   = (_Float16*)alloc((size_t)N * 128 * 2);
    _Float16* x2h  = (_Float16*)alloc((size_t)N * 768 * 2);
    _Float16* w1t  = (_Float16*)alloc((size_t)768 * 128 * 2);
    _Float16* w2t  = (_Float16*)alloc((size_t)384 * 768 * 2);
    float* alS1 = (float*)alloc((size_t)N * 3 * 4);
    float* alD1 = (float*)alloc((size_t)N * 3 * 4);
    float* alS2 = (float*)alloc((size_t)N * 4);
    float* alD2 = (float*)alloc((size_t)N * 4);
    int* deg    = (int*)alloc((size_t)N * 4);
    int* rowptr = (int*)alloc((size_t)(N + 1) * 4);
    int* cursor = (int*)alloc((size_t)N * 4);
    int* csrs   = (int*)alloc((size_t)ET * 4);

    // CSR by destination (shared by both layers)
    hipMemsetAsync(deg, 0, (size_t)N * 4, stream);
    k_hist<<<(ET + 255) / 256, 256, 0, stream>>>(dst, E, N, deg);
    k_scan<<<1, 256, 0, stream>>>(deg, rowptr, cursor, N);
    k_scatter<<<(ET + 255) / 256, 256, 0, stream>>>(src, dst, E, N, cursor, csrs);

    // operand prep (fp16)
    int n8 = N * 128 / 8;
    k_f2h8<<<(n8 + 255) / 256, 256, 0, stream>>>(x, xh, n8);
    k_transpose_h<<<(128 * 768 + 255) / 256, 256, 0, stream>>>(W1, w1t, 128, 768);
    k_transpose_h<<<(768 * 384 + 255) / 256, 256, 0, stream>>>(W2, w2t, 768, 384);

    // layer 1
    dim3 g1(768 / 128, (N + 127) / 128);
    k_hgemm<_Float16><<<g1, 256, 0, stream>>>(xh, w1t, h1, N, 768, 128);
    k_att<3, 256><<<(N * 3 + 3) / 4, 256, 0, stream>>>(h1, as1, ad1, alS1, alD1, N);
    k_aggw<3, 256, _Float16><<<(N + 3) / 4, 256, 0, stream>>>(h1, alS1, alD1, rowptr, csrs, b1, x2h, N);

    // layer 2
    dim3 g2(384 / 128, (N + 127) / 128);
    k_hgemm<_Float16><<<g2, 256, 0, stream>>>(x2h, w2t, h2, N, 384, 768);
    k_att<1, 384><<<(N + 3) / 4, 256, 0, stream>>>(h2, as2, ad2, alS2, alD2, N);
    k_aggw<1, 384, float><<<(N + 3) / 4, 256, 0, stream>>>(h2, alS2, alD2, rowptr, csrs, b2, out, N);
}

// Round 5
// 276.098 us; speedup vs baseline: 2.3443x; 1.0275x over previous
//
#include <hip/hip_runtime.h>
#include <hip/hip_bf16.h>

#define NEG_SLOPE 0.2f

typedef _Float16 half8 __attribute__((ext_vector_type(8)));
typedef _Float16 half4v __attribute__((ext_vector_type(4)));
typedef _Float16 half2v __attribute__((ext_vector_type(2)));
typedef float floatx4 __attribute__((ext_vector_type(4)));
typedef float floatx2 __attribute__((ext_vector_type(2)));

// ---------------------------------------------------------------- CSR build
__global__ void k_hist(const int* __restrict__ dst, int E, int n, int* __restrict__ deg) {
    int e = blockIdx.x * blockDim.x + threadIdx.x;
    int ET = E + n;
    if (e >= ET) return;
    int d = (e < E) ? dst[e] : (e - E);   // self-loops appended
    atomicAdd(&deg[d], 1);
}

__global__ void k_scan(const int* __restrict__ deg, int* __restrict__ rowptr,
                       int* __restrict__ cursor, int n) {
    __shared__ int part[256];
    int t = threadIdx.x;
    int chunk = (n + 255) / 256;
    int s0 = t * chunk, s1 = min(s0 + chunk, n);
    int s = 0;
    for (int i = s0; i < s1; ++i) s += deg[i];
    part[t] = s;
    __syncthreads();
    for (int off = 1; off < 256; off <<= 1) {
        int v = (t >= off) ? part[t - off] : 0;
        __syncthreads();
        part[t] += v;
        __syncthreads();
    }
    int run = (t == 0) ? 0 : part[t - 1];
    for (int i = s0; i < s1; ++i) { rowptr[i] = run; cursor[i] = run; run += deg[i]; }
    if (t == 255) rowptr[n] = run;
}

__global__ void k_scatter(const int* __restrict__ src, const int* __restrict__ dst,
                          int E, int n, int* __restrict__ cursor, int* __restrict__ csr_src) {
    int e = blockIdx.x * blockDim.x + threadIdx.x;
    int ET = E + n;
    if (e >= ET) return;
    int s = (e < E) ? src[e] : (e - E);
    int d = (e < E) ? dst[e] : (e - E);
    int pos = atomicAdd(&cursor[d], 1);
    csr_src[pos] = s;
}

// ------------------------------------------------------------- conversions
__global__ void k_f2h8(const float* __restrict__ in, _Float16* __restrict__ out, int n8) {
    int i = blockIdx.x * 256 + threadIdx.x;
    if (i >= n8) return;
    const float4* p = (const float4*)in + (size_t)i * 2;
    float4 a = p[0], b = p[1];
    _Float16 h[8] = {(_Float16)a.x, (_Float16)a.y, (_Float16)a.z, (_Float16)a.w,
                     (_Float16)b.x, (_Float16)b.y, (_Float16)b.z, (_Float16)b.w};
    *(uint4*)(out + (size_t)i * 8) = *(const uint4*)h;
}

// W[R][C] fp32 -> Wt[C][R] fp16
__global__ void k_transpose_h(const float* __restrict__ W, _Float16* __restrict__ Wt,
                              int R, int C) {
    int i = blockIdx.x * 256 + threadIdx.x;
    if (i >= R * C) return;
    int c = i / R, r = i % R;
    Wt[i] = (_Float16)W[(size_t)r * C + c];
}

// ------------------------------------------------------------ fp16 MFMA GEMM
__device__ __forceinline__ void gload_lds16(const _Float16* g, _Float16* l) {
    __builtin_amdgcn_global_load_lds((const __attribute__((address_space(1))) void*)g,
                                     (__attribute__((address_space(3))) void*)l,
                                     16, 0, 0);
}

template <typename OutT>
__global__ __launch_bounds__(256) void k_hgemm(const _Float16* __restrict__ A,
                                               const _Float16* __restrict__ Bt,
                                               OutT* __restrict__ C,
                                               int M, int N, int K) {
    __shared__ _Float16 lds[2 * 8192];       // [buf][A:4096|B:4096] elems (32KB)
    int t = threadIdx.x;
    int lane = t & 63, w = t >> 6;
    int wr = w >> 1, wc = w & 1;
    int lrow = lane & 15, lko = lane >> 4;
    int row0 = blockIdx.y * 128, col0 = blockIdx.x * 128;

    int sr = t & 127;
    int sko = t >> 7;
    int agr = row0 + sr; if (agr >= M) agr = M - 1;
    const _Float16* aRow = A + (size_t)agr * K;
    const _Float16* bRow = Bt + (size_t)(col0 + sr) * K;

    floatx4 acc[4][4] = {};

    int nk = K >> 5;
#pragma unroll
    for (int s = 0; s < 2; ++s) {
        int ko = s * 2 + sko;
        gload_lds16(aRow + ko * 8, lds + s * 2048 + t * 8);
        gload_lds16(bRow + ko * 8, lds + 4096 + s * 2048 + t * 8);
    }
    __syncthreads();

    for (int ks = 0; ks < nk; ++ks) {
        int buf = ks & 1;
        if (ks + 1 < nk) {
            int kt = (ks + 1) << 5;
            _Float16* dstb = lds + (buf ^ 1) * 8192;
#pragma unroll
            for (int s = 0; s < 2; ++s) {
                int ko = s * 2 + sko;
                gload_lds16(aRow + kt + ko * 8, dstb + s * 2048 + t * 8);
                gload_lds16(bRow + kt + ko * 8, dstb + 4096 + s * 2048 + t * 8);
            }
        }
        const _Float16* base = lds + buf * 8192 + lko * 1024;
        half8 af[4], bf[4];
#pragma unroll
        for (int mi = 0; mi < 4; ++mi)
            af[mi] = *(const half8*)(base + (wr * 64 + mi * 16 + lrow) * 8);
#pragma unroll
        for (int ni = 0; ni < 4; ++ni)
            bf[ni] = *(const half8*)(base + 4096 + (wc * 64 + ni * 16 + lrow) * 8);
#pragma unroll
        for (int mi = 0; mi < 4; ++mi)
#pragma unroll
            for (int ni = 0; ni < 4; ++ni)
                acc[mi][ni] = __builtin_amdgcn_mfma_f32_16x16x32_f16(
                    af[mi], bf[ni], acc[mi][ni], 0, 0, 0);
        __syncthreads();
    }

#pragma unroll
    for (int mi = 0; mi < 4; ++mi) {
        int rb = row0 + wr * 64 + mi * 16 + lko * 4;
#pragma unroll
        for (int ni = 0; ni < 4; ++ni) {
            int col = col0 + wc * 64 + ni * 16 + lrow;
#pragma unroll
            for (int j = 0; j < 4; ++j) {
                int row = rb + j;
                if (row < M) C[(size_t)row * N + col] = (OutT)acc[mi][ni][j];
            }
        }
    }
}

// ------------------------------------------------------- attention logit dots
template <int H, int C>
__global__ __launch_bounds__(256) void k_att(const _Float16* __restrict__ h,
                      const float* __restrict__ as, const float* __restrict__ ad,
                      float* __restrict__ al_s, float* __restrict__ al_d, int n) {
    int wid = (blockIdx.x * blockDim.x + threadIdx.x) >> 6;
    int lane = threadIdx.x & 63;
    if (wid >= n * H) return;
    int node = wid / H, hh = wid % H;
    const _Float16* hp = h + (size_t)node * H * C + hh * C;
    const float* sp = as + hh * C;
    const float* dp = ad + hh * C;
    float aS, aD;
    {
        half4v v = *(const half4v*)(hp + lane * 4);
        float4 a = *(const float4*)(sp + lane * 4);
        float4 d = *(const float4*)(dp + lane * 4);
        float f0 = (float)v[0], f1 = (float)v[1], f2 = (float)v[2], f3 = (float)v[3];
        aS = f0 * a.x + f1 * a.y + f2 * a.z + f3 * a.w;
        aD = f0 * d.x + f1 * d.y + f2 * d.z + f3 * d.w;
    }
    if constexpr (C == 384) {
        half2v v = *(const half2v*)(hp + 256 + lane * 2);
        floatx2 a = *(const floatx2*)(sp + 256 + lane * 2);
        floatx2 d = *(const floatx2*)(dp + 256 + lane * 2);
        aS += (float)v[0] * a[0] + (float)v[1] * a[1];
        aD += (float)v[0] * d[0] + (float)v[1] * d[1];
    }
#pragma unroll
    for (int off = 32; off; off >>= 1) {
        aS += __shfl_xor(aS, off);
        aD += __shfl_xor(aD, off);
    }
    if (lane == 0) { al_s[wid] = aS; al_d[wid] = aD; }
}

// ----------------------------------------------- per-node softmax + aggregate
// ONE WAVE PER DST NODE, 4x edge-unrolled gather (8 VMEM in flight).
template <int H, int C, typename OutT>
__global__ __launch_bounds__(256) void k_aggw(const _Float16* __restrict__ h,
                                              const float* __restrict__ al_s,
                                              const float* __restrict__ al_d,
                                              const int* __restrict__ rowptr,
                                              const int* __restrict__ csr_src,
                                              const float* __restrict__ bias,
                                              OutT* __restrict__ out, int n) {
    constexpr int HC = H * C;
    constexpr int CA = HC / 96;    // 8 (HC=768) or 4 (HC=384)
    constexpr int CB = CA / 2;
    int wid = (blockIdx.x * blockDim.x + threadIdx.x) >> 6;
    int lane = threadIdx.x & 63;
    if (wid >= n) return;
    int beg = rowptr[wid], end = rowptr[wid + 1];

    float ald[H];
#pragma unroll
    for (int hh = 0; hh < H; ++hh) ald[hh] = al_d[wid * H + hh];

    // pass 1: per-head max
    float m[H];
#pragma unroll
    for (int hh = 0; hh < H; ++hh) m[hh] = -1e30f;
    for (int base = beg; base < end; base += 64) {
        int i = base + lane;
        if (i < end) {
            int s = csr_src[i];
#pragma unroll
            for (int hh = 0; hh < H; ++hh) {
                float e = al_s[s * H + hh] + ald[hh];
                e = e > 0.f ? e : NEG_SLOPE * e;
                m[hh] = fmaxf(m[hh], e);
            }
        }
    }
#pragma unroll
    for (int hh = 0; hh < H; ++hh)
#pragma unroll
        for (int off = 32; off; off >>= 1) m[hh] = fmaxf(m[hh], __shfl_xor(m[hh], off));

    // pass 2: denominator
    float sm[H];
#pragma unroll
    for (int hh = 0; hh < H; ++hh) sm[hh] = 0.f;
    for (int base = beg; base < end; base += 64) {
        int i = base + lane;
        if (i < end) {
            int s = csr_src[i];
#pragma unroll
            for (int hh = 0; hh < H; ++hh) {
                float e = al_s[s * H + hh] + ald[hh];
                e = e > 0.f ? e : NEG_SLOPE * e;
                sm[hh] += __expf(e - m[hh]);
            }
        }
    }
    float inv[H];
#pragma unroll
    for (int hh = 0; hh < H; ++hh) {
#pragma unroll
        for (int off = 32; off; off >>= 1) sm[hh] += __shfl_xor(sm[hh], off);
        inv[hh] = 1.f / sm[hh];
    }

    // pass 3: gather + weighted accumulate, 4 edges per step
    float accA[CA] = {}, accB[CB] = {};
    for (int base = beg; base < end; base += 64) {
        int cnt = min(64, end - base);
        int i = base + lane;
        int sl = (i < end) ? csr_src[i] : 0;
        float ex[H];
#pragma unroll
        for (int hh = 0; hh < H; ++hh) {
            float e = al_s[sl * H + hh] + ald[hh];
            e = e > 0.f ? e : NEG_SLOPE * e;
            ex[hh] = (i < end) ? __expf(e - m[hh]) * inv[hh] : 0.f;
        }
        int j = 0;
        for (; j + 4 <= cnt; j += 4) {
            int ss0, ss1, ss2, ss3;
            float wA0, wA1, wA2, wA3, wB0, wB1, wB2, wB3;
            ss0 = __shfl(sl, j + 0); ss1 = __shfl(sl, j + 1);
            ss2 = __shfl(sl, j + 2); ss3 = __shfl(sl, j + 3);
            if constexpr (H == 3) {
                float a0 = __shfl(ex[0], j + 0), b0 = __shfl(ex[1], j + 0), c0 = __shfl(ex[2], j + 0);
                float a1 = __shfl(ex[0], j + 1), b1 = __shfl(ex[1], j + 1), c1 = __shfl(ex[2], j + 1);
                float a2 = __shfl(ex[0], j + 2), b2 = __shfl(ex[1], j + 2), c2 = __shfl(ex[2], j + 2);
                float a3 = __shfl(ex[0], j + 3), b3 = __shfl(ex[1], j + 3), c3 = __shfl(ex[2], j + 3);
                wA0 = (lane < 32) ? a0 : b0; wB0 = c0;
                wA1 = (lane < 32) ? a1 : b1; wB1 = c1;
                wA2 = (lane < 32) ? a2 : b2; wB2 = c2;
                wA3 = (lane < 32) ? a3 : b3; wB3 = c3;
            } else {
                wA0 = wB0 = __shfl(ex[0], j + 0);
                wA1 = wB1 = __shfl(ex[0], j + 1);
                wA2 = wB2 = __shfl(ex[0], j + 2);
                wA3 = wB3 = __shfl(ex[0], j + 3);
            }
            const _Float16* r0 = h + (size_t)ss0 * HC;
            const _Float16* r1 = h + (size_t)ss1 * HC;
            const _Float16* r2 = h + (size_t)ss2 * HC;
            const _Float16* r3 = h + (size_t)ss3 * HC;
            if constexpr (CA == 8) {
                half8 va0 = *(const half8*)(r0 + lane * 8);
                half8 va1 = *(const half8*)(r1 + lane * 8);
                half8 va2 = *(const half8*)(r2 + lane * 8);
                half8 va3 = *(const half8*)(r3 + lane * 8);
                half4v vb0 = *(const half4v*)(r0 + 512 + lane * 4);
                half4v vb1 = *(const half4v*)(r1 + 512 + lane * 4);
                half4v vb2 = *(const half4v*)(r2 + 512 + lane * 4);
                half4v vb3 = *(const half4v*)(r3 + 512 + lane * 4);
#pragma unroll
                for (int k = 0; k < 8; ++k) {
                    accA[k] = fmaf(wA0, (float)va0[k], accA[k]);
                    accA[k] = fmaf(wA1, (float)va1[k], accA[k]);
                    accA[k] = fmaf(wA2, (float)va2[k], accA[k]);
                    accA[k] = fmaf(wA3, (float)va3[k], accA[k]);
                }
#pragma unroll
                for (int k = 0; k < 4; ++k) {
                    accB[k] = fmaf(wB0, (float)vb0[k], accB[k]);
                    accB[k] = fmaf(wB1, (float)vb1[k], accB[k]);
                    accB[k] = fmaf(wB2, (float)vb2[k], accB[k]);
                    accB[k] = fmaf(wB3, (float)vb3[k], accB[k]);
                }
            } else {
                half4v va0 = *(const half4v*)(r0 + lane * 4);
                half4v va1 = *(const half4v*)(r1 + lane * 4);
                half4v va2 = *(const half4v*)(r2 + lane * 4);
                half4v va3 = *(const half4v*)(r3 + lane * 4);
                half2v vb0 = *(const half2v*)(r0 + 256 + lane * 2);
                half2v vb1 = *(const half2v*)(r1 + 256 + lane * 2);
                half2v vb2 = *(const half2v*)(r2 + 256 + lane * 2);
                half2v vb3 = *(const half2v*)(r3 + 256 + lane * 2);
#pragma unroll
                for (int k = 0; k < 4; ++k) {
                    accA[k] = fmaf(wA0, (float)va0[k], accA[k]);
                    accA[k] = fmaf(wA1, (float)va1[k], accA[k]);
                    accA[k] = fmaf(wA2, (float)va2[k], accA[k]);
                    accA[k] = fmaf(wA3, (float)va3[k], accA[k]);
                }
#pragma unroll
                for (int k = 0; k < 2; ++k) {
                    accB[k] = fmaf(wB0, (float)vb0[k], accB[k]);
                    accB[k] = fmaf(wB1, (float)vb1[k], accB[k]);
                    accB[k] = fmaf(wB2, (float)vb2[k], accB[k]);
                    accB[k] = fmaf(wB3, (float)vb3[k], accB[k]);
                }
            }
        }
        for (; j < cnt; ++j) {
            int s = __shfl(sl, j);
            float aA, aB;
            if constexpr (H == 3) {
                float s0 = __shfl(ex[0], j);
                float s1 = __shfl(ex[1], j);
                float s2 = __shfl(ex[2], j);
                aA = (lane < 32) ? s0 : s1;
                aB = s2;
            } else {
                aA = aB = __shfl(ex[0], j);
            }
            const _Float16* row = h + (size_t)s * HC;
            if constexpr (CA == 8) {
                half8 va = *(const half8*)(row + lane * 8);
                half4v vb = *(const half4v*)(row + 512 + lane * 4);
#pragma unroll
                for (int k = 0; k < 8; ++k) accA[k] = fmaf(aA, (float)va[k], accA[k]);
#pragma unroll
                for (int k = 0; k < 4; ++k) accB[k] = fmaf(aB, (float)vb[k], accB[k]);
            } else {
                half4v va = *(const half4v*)(row + lane * 4);
                half2v vb = *(const half2v*)(row + 256 + lane * 2);
#pragma unroll
                for (int k = 0; k < 4; ++k) accA[k] = fmaf(aA, (float)va[k], accA[k]);
#pragma unroll
                for (int k = 0; k < 2; ++k) accB[k] = fmaf(aB, (float)vb[k], accB[k]);
            }
        }
    }

    // epilogue: bias + relu, vectorized store
    size_t obase = (size_t)wid * HC;
    int cA0 = lane * CA, cB0 = 64 * CA + lane * CB;
    if constexpr (sizeof(OutT) == 2) {
        _Float16* op = (_Float16*)out;
        if constexpr (CA == 8) {
            half8 oa;
#pragma unroll
            for (int k = 0; k < 8; ++k) {
                float v = accA[k] + bias[cA0 + k];
                oa[k] = (_Float16)(v > 0.f ? v : 0.f);
            }
            *(half8*)(op + obase + cA0) = oa;
            half4v ob;
#pragma unroll
            for (int k = 0; k < 4; ++k) {
                float v = accB[k] + bias[cB0 + k];
                ob[k] = (_Float16)(v > 0.f ? v : 0.f);
            }
            *(half4v*)(op + obase + cB0) = ob;
        } else {
            half4v oa;
#pragma unroll
            for (int k = 0; k < 4; ++k) {
                float v = accA[k] + bias[cA0 + k];
                oa[k] = (_Float16)(v > 0.f ? v : 0.f);
            }
            *(half4v*)(op + obase + cA0) = oa;
            half2v ob;
#pragma unroll
            for (int k = 0; k < 2; ++k) {
                float v = accB[k] + bias[cB0 + k];
                ob[k] = (_Float16)(v > 0.f ? v : 0.f);
            }
            *(half2v*)(op + obase + cB0) = ob;
        }
    } else {
        float* op = (float*)out;
        if constexpr (CA == 4) {
            float4 oa;
            float t0 = accA[0] + bias[cA0 + 0]; oa.x = t0 > 0.f ? t0 : 0.f;
            float t1 = accA[1] + bias[cA0 + 1]; oa.y = t1 > 0.f ? t1 : 0.f;
            float t2 = accA[2] + bias[cA0 + 2]; oa.z = t2 > 0.f ? t2 : 0.f;
            float t3 = accA[3] + bias[cA0 + 3]; oa.w = t3 > 0.f ? t3 : 0.f;
            *(float4*)(op + obase + cA0) = oa;
            floatx2 ob;
            float u0 = accB[0] + bias[cB0 + 0]; ob[0] = u0 > 0.f ? u0 : 0.f;
            float u1 = accB[1] + bias[cB0 + 1]; ob[1] = u1 > 0.f ? u1 : 0.f;
            *(floatx2*)(op + obase + cB0) = ob;
        } else {
#pragma unroll
            for (int k = 0; k < CA; ++k) {
                float v = accA[k] + bias[cA0 + k];
                op[obase + cA0 + k] = v > 0.f ? v : 0.f;
            }
#pragma unroll
            for (int k = 0; k < CB; ++k) {
                float v = accB[k] + bias[cB0 + k];
                op[obase + cB0 + k] = v > 0.f ? v : 0.f;
            }
        }
    }
}

// ---------------------------------------------------------------------- host
extern "C" void kernel_launch(void* const* d_in, const int* in_sizes, int n_in,
                              void* d_out, int out_size, void* d_ws, size_t ws_size,
                              hipStream_t stream) {
    const float* x   = (const float*)d_in[0];
    const int*   ei  = (const int*)d_in[1];
    const float* W1  = (const float*)d_in[2];
    const float* as1 = (const float*)d_in[3];
    const float* ad1 = (const float*)d_in[4];
    const float* b1  = (const float*)d_in[5];
    const float* W2  = (const float*)d_in[6];
    const float* as2 = (const float*)d_in[7];
    const float* ad2 = (const float*)d_in[8];
    const float* b2  = (const float*)d_in[9];
    float* out = (float*)d_out;

    const int N  = in_sizes[0] / 128;   // 20000
    const int E  = in_sizes[1] / 2;     // 320000
    const int ET = E + N;
    const int* src = ei;
    const int* dst = ei + E;

    char* ws = (char*)d_ws;
    size_t off = 0;
    auto alloc = [&](size_t bytes) {
        void* p = ws + off;
        off = (off + bytes + 255) & ~(size_t)255;
        return p;
    };
    _Float16* h1   = (_Float16*)alloc((size_t)N * 768 * 2);
    _Float16* h2   = (_Float16*)alloc((size_t)N * 384 * 2);
    _Float16* xh   = (_Float16*)alloc((size_t)N * 128 * 2);
    _Float16* x2h  = (_Float16*)alloc((size_t)N * 768 * 2);
    _Float16* w1t  = (_Float16*)alloc((size_t)768 * 128 * 2);
    _Float16* w2t  = (_Float16*)alloc((size_t)384 * 768 * 2);
    float* alS1 = (float*)alloc((size_t)N * 3 * 4);
    float* alD1 = (float*)alloc((size_t)N * 3 * 4);
    float* alS2 = (float*)alloc((size_t)N * 4);
    float* alD2 = (float*)alloc((size_t)N * 4);
    int* deg    = (int*)alloc((size_t)N * 4);
    int* rowptr = (int*)alloc((size_t)(N + 1) * 4);
    int* cursor = (int*)alloc((size_t)N * 4);
    int* csrs   = (int*)alloc((size_t)ET * 4);

    // CSR by destination (shared by both layers)
    hipMemsetAsync(deg, 0, (size_t)N * 4, stream);
    k_hist<<<(ET + 255) / 256, 256, 0, stream>>>(dst, E, N, deg);
    k_scan<<<1, 256, 0, stream>>>(deg, rowptr, cursor, N);
    k_scatter<<<(ET + 255) / 256, 256, 0, stream>>>(src, dst, E, N, cursor, csrs);

    // operand prep (fp16)
    int n8 = N * 128 / 8;
    k_f2h8<<<(n8 + 255) / 256, 256, 0, stream>>>(x, xh, n8);
    k_transpose_h<<<(128 * 768 + 255) / 256, 256, 0, stream>>>(W1, w1t, 128, 768);
    k_transpose_h<<<(768 * 384 + 255) / 256, 256, 0, stream>>>(W2, w2t, 768, 384);

    // layer 1
    dim3 g1(768 / 128, (N + 127) / 128);
    k_hgemm<_Float16><<<g1, 256, 0, stream>>>(xh, w1t, h1, N, 768, 128);
    k_att<3, 256><<<(N * 3 + 3) / 4, 256, 0, stream>>>(h1, as1, ad1, alS1, alD1, N);
    k_aggw<3, 256, _Float16><<<(N + 3) / 4, 256, 0, stream>>>(h1, alS1, alD1, rowptr, csrs, b1, x2h, N);

    // layer 2
    dim3 g2(384 / 128, (N + 127) / 128);
    k_hgemm<_Float16><<<g2, 256, 0, stream>>>(x2h, w2t, h2, N, 384, 768);
    k_att<1, 384><<<(N + 3) / 4, 256, 0, stream>>>(h2, as2, ad2, alS2, alD2, N);
    k_aggw<1, 384, float><<<(N + 3) / 4, 256, 0, stream>>>(h2, alS2, alD2, rowptr, csrs, b2, out, N);
}